// Round 10
// baseline (78.473 us; speedup 1.0000x reference)
//
#include <hip/hip_runtime.h>
#include <math.h>

#define NBATCH 128
#define NP 256
#define NC 64
#define KNN 16
#define EPSV 1e-3f

typedef __bf16 bf16_t;
typedef bf16_t bf16x8 __attribute__((ext_vector_type(8)));
typedef float f32x4 __attribute__((ext_vector_type(4)));

static __device__ __forceinline__ f32x4 mfma16(bf16x8 a, bf16x8 b, f32x4 c) {
    return __builtin_amdgcn_mfma_f32_16x16x32_bf16(a, b, c, 0, 0, 0);
}
static __device__ __forceinline__ unsigned short f2bfu(float f) {
    union { bf16_t b; unsigned short u; } cv; cv.b = (bf16_t)f; return cv.u;
}
static __device__ __forceinline__ unsigned umin2(unsigned a, unsigned b) { return a < b ? a : b; }
static __device__ __forceinline__ unsigned umax2(unsigned a, unsigned b) { return a > b ? a : b; }
// Wave-private LDS ordering fence (per-wave lgkmcnt; memory clobber pins ds order)
#define LDS_FENCE() asm volatile("s_waitcnt lgkmcnt(0)" ::: "memory")

// Sorted-ascending insert, med3 form: since bk[i-1] <= bk[i],
// new bk[i] = min(max(key, bk[i-1]), bk[i])  (= v_med3_u32). 2 ops/level.
// Descending ii reads old bk[ii-1]. Keys unique (idx in low bits).
#define INSERTK(k_)                                                   \
    do {                                                              \
        _Pragma("unroll")                                             \
        for (int ii = KNN - 1; ii >= 1; --ii)                         \
            bk[ii] = umin2(umax2((k_), bk[ii - 1]), bk[ii]);          \
        bk[0] = umin2((k_), bk[0]);                                   \
    } while (0)

// ---------------------------------------------------------------------------
// kNN: packed u32 (dist|idx) keys, f32 cancellation-free distances, 2-way
// candidate split, med3 insertion network. Grid = 2*NBATCH blocks of 256 thr.
// ---------------------------------------------------------------------------
__global__ __launch_bounds__(256) void knn_kernel(const float* __restrict__ points,
                                                  int* __restrict__ idx_out) {
    const int bb = blockIdx.x >> 1;
    const int qbase = (blockIdx.x & 1) * 128;
    const int t = threadIdx.x;
    const int qt = t & 127;
    const int half = t >> 7;
    const int p = qbase + qt;            // my query (within batch)

    __shared__ __align__(16) float4 sp[NP];
    __shared__ unsigned sk[128][17];

    const float* pb = points + (size_t)bb * NP * 3;
    sp[t] = make_float4(pb[t * 3 + 0], pb[t * 3 + 1], pb[t * 3 + 2], 0.f);
    __syncthreads();

    const float4 qp = sp[p];
    unsigned bk[KNN];
#pragma unroll
    for (int i = 0; i < KNN; ++i) bk[i] = 0xFFFFFFFFu;

    const int cbase = half * 128;        // wave-uniform
#pragma unroll 4
    for (int c = 0; c < 128; ++c) {
        const int cand = cbase + c;
        const float4 P = sp[cand];       // wave-uniform addr -> LDS broadcast
        const float dx = qp.x - P.x, dy = qp.y - P.y, dz = qp.z - P.z;
        const float d = fmaf(dx, dx, fmaf(dy, dy, dz * dz));
        unsigned key = (__float_as_uint(d) & 0xFFFFFF00u) | (unsigned)cand;
        key = (cand == p) ? 0xFFFFFFFFu : key;   // self-exclusion, branchless
        INSERTK(key);
    }

    if (half == 1) {
#pragma unroll
        for (int i = 0; i < KNN; ++i) sk[qt][i] = bk[i];
    }
    __syncthreads();
    if (half == 0) {
        for (int j = 0; j < KNN; ++j) {
            const unsigned key = sk[qt][j];
            if (key >= bk[KNN - 1]) break;   // ascending -> rest can't qualify
            INSERTK(key);
        }
        int* op = idx_out + ((size_t)bb * NP + p) * KNN;
#pragma unroll
        for (int i = 0; i < KNN; ++i) op[i] = (int)(bk[i] & 0xFFu);
    }
}

// ---------------------------------------------------------------------------
// fcvt: features f32 -> bf16 once.
// ---------------------------------------------------------------------------
__global__ __launch_bounds__(256) void fcvt_kernel(const float* __restrict__ f,
                                                   unsigned short* __restrict__ o) {
    const int tid = blockIdx.x * 256 + threadIdx.x;
    const float4 a = ((const float4*)f)[tid * 2];
    const float4 b = ((const float4*)f)[tid * 2 + 1];
    union { unsigned short s[8]; uint4 v; } r;
    r.s[0] = f2bfu(a.x); r.s[1] = f2bfu(a.y); r.s[2] = f2bfu(a.z); r.s[3] = f2bfu(a.w);
    r.s[4] = f2bfu(b.x); r.s[5] = f2bfu(b.y); r.s[6] = f2bfu(b.z); r.s[7] = f2bfu(b.w);
    ((uint4*)o)[tid] = r.v;
}

// ---------------------------------------------------------------------------
// Prep: weights in MFMA B-fragment order (bf16) + folded BN params.
// B-frag (16x16x32): lane l holds B[ks*32 + (l>>4)*8 + j][t*16 + (l&15)].
// wsf regions (u16 offsets), 8 frags each:
//   V [0,4096) = w0lo-w0hi ; w0hi [4096,8192) ; w1 [8192,12288) ;
//   w2 [12288,16384) ; ws [16384,20480)
// bnp: scl[192], shf[192], sscl[64], sshf[64].
// ---------------------------------------------------------------------------
__global__ __launch_bounds__(256) void prep_kernel(
    const float* __restrict__ w0, const float* __restrict__ w1,
    const float* __restrict__ w2, const float* __restrict__ sc_w,
    const float* __restrict__ gammas, const float* __restrict__ betas,
    const float* __restrict__ means, const float* __restrict__ variances,
    const float* __restrict__ sc_gamma, const float* __restrict__ sc_beta,
    const float* __restrict__ sc_mean, const float* __restrict__ sc_var,
    unsigned short* __restrict__ wsf, float* __restrict__ bnp)
{
    const int tid = blockIdx.x * 256 + threadIdx.x;
    if (tid < 20480) {
        const int region = tid >> 12;          // 0:V 1:w0hi 2:w1 3:w2 4:ws
        const int e2 = tid & 4095;
        const int f = e2 >> 9;                 // frag 0..7
        const int r = e2 & 511;
        const int lane = r >> 3, j = r & 7;
        const int ks = f >> 2, t = f & 3;
        const int row = ks * 32 + (lane >> 4) * 8 + j;
        const int col = t * 16 + (lane & 15);
        float v;
        if (region == 0)      v = w0[row * 64 + col] - w0[(64 + row) * 64 + col];
        else if (region == 1) v = w0[(64 + row) * 64 + col];
        else if (region == 2) v = w1[row * 64 + col];
        else if (region == 3) v = w2[row * 64 + col];
        else                  v = sc_w[row * 64 + col];
        wsf[tid] = f2bfu(v);
    } else {
        const int e = tid - 20480;
        if (e < 192) {
            float s = gammas[e] * rsqrtf(variances[e] + EPSV);
            bnp[e] = s;
            bnp[192 + e] = betas[e] - means[e] * s;
        } else if (e < 256) {
            const int d = e - 192;
            float s = sc_gamma[d] * rsqrtf(sc_var[d] + EPSV);
            bnp[384 + d] = s;
            bnp[448 + d] = sc_beta[d] - sc_mean[d] * s;
        }
    }
}

// ---------------------------------------------------------------------------
// Edge MLP v6: phase-batched layers. 2 independent waves/WG; wave owns 8
// points processed as 2 groups of 4. Per group: {4x gather+L1} FENCE
// {4x L2 in-place} FENCE {4x L3+reduce} FENCE. Fences: 24 -> ~7 per wave;
// 4 independent tile-chains between fences (ILP instead of occupancy).
// ---------------------------------------------------------------------------
__global__ __launch_bounds__(128, 3) void edge_kernel(
    const unsigned short* __restrict__ fbf, const int* __restrict__ knn_idx,
    const unsigned short* __restrict__ wsf, const float* __restrict__ bnp,
    float* __restrict__ out)
{
    __shared__ __align__(16) unsigned short slab[2][4][16 * 72];  // 18.4 KB
    __shared__ float s0buf[2][8][64];    // center term (k-invariant)  4 KB
    __shared__ float ftsbuf[2][8][64];   // mean-over-k results        4 KB

    const int tid = threadIdx.x;
    const int wid = tid >> 6;
    const int l = tid & 63;
    const int i = l & 15;
    const int h = l >> 4;
    // bijective XCD swizzle: 2048 blocks = 8 XCDs x 256 contiguous work items
    const int wg = (blockIdx.x & 7) * 256 + (blockIdx.x >> 3);
    const int p0 = (wg * 2 + wid) * 8;
    const int b = p0 >> 8;

    const bf16x8* __restrict__ WV = (const bf16x8*)(wsf);
    const bf16x8* __restrict__ W0H = (const bf16x8*)(wsf + 4096);
    const bf16x8* __restrict__ W1 = (const bf16x8*)(wsf + 8192);
    const bf16x8* __restrict__ W2 = (const bf16x8*)(wsf + 12288);

    // main-loop weights resident in registers (24 frags = 96 VGPR)
    bf16x8 w0h[2][4], w1r[2][4], w2r[2][4];
#pragma unroll
    for (int ks = 0; ks < 2; ++ks)
#pragma unroll
        for (int t = 0; t < 4; ++t) {
            w0h[ks][t] = W0H[(ks * 4 + t) * 64 + l];
            w1r[ks][t] = W1[(ks * 4 + t) * 64 + l];
            w2r[ks][t] = W2[(ks * 4 + t) * 64 + l];
        }

    float scl[3][4], shf[3][4];
#pragma unroll
    for (int L = 0; L < 3; ++L)
#pragma unroll
        for (int t = 0; t < 4; ++t) {
            scl[L][t] = bnp[L * 64 + t * 16 + i];
            shf[L][t] = bnp[192 + L * 64 + t * 16 + i];
        }

    // ---- prologue: s0 = ctr @ V for this wave's 8 points (rows 8..15 dup) ----
    {
        const unsigned short* cp = fbf + (size_t)(p0 + (i & 7)) * NC;
        bf16x8 a0 = *(const bf16x8*)(cp + 8 * h);
        bf16x8 a1 = *(const bf16x8*)(cp + 32 + 8 * h);
#pragma unroll
        for (int t = 0; t < 4; ++t) {
            f32x4 acc = {0.f, 0.f, 0.f, 0.f};
            acc = mfma16(a0, WV[t * 64 + l], acc);
            acc = mfma16(a1, WV[(4 + t) * 64 + l], acc);
            if (h < 2) {
#pragma unroll
                for (int r = 0; r < 4; ++r)
                    s0buf[wid][h * 4 + r][t * 16 + i] = acc[r];
            }
        }
    }
    int nks[8];
#pragma unroll
    for (int q = 0; q < 8; ++q) nks[q] = knn_idx[(size_t)(p0 + q) * KNN + i];
    LDS_FENCE();

#pragma unroll
    for (int g = 0; g < 2; ++g) {
        const int qb = g * 4;
        // ---- gather all 4 neighbor A-fragment pairs (independent loads) ----
        bf16x8 fc[4][2];
#pragma unroll
        for (int qq = 0; qq < 4; ++qq) {
            const unsigned short* sp = fbf + (size_t)(b * NP + nks[qb + qq]) * NC;
            fc[qq][0] = *(const bf16x8*)(sp + 8 * h);
            fc[qq][1] = *(const bf16x8*)(sp + 32 + 8 * h);
        }
        // ---- L1 phase: 4 independent tiles -> slab[wid][qq] ----
#pragma unroll
        for (int qq = 0; qq < 4; ++qq) {
            float s0q[4];
#pragma unroll
            for (int t = 0; t < 4; ++t) s0q[t] = s0buf[wid][qb + qq][t * 16 + i];
            unsigned short* sl = slab[wid][qq];
#pragma unroll
            for (int t = 0; t < 4; ++t) {
                f32x4 acc = {0.f, 0.f, 0.f, 0.f};
                acc = mfma16(fc[qq][0], w0h[0][t], acc);
                acc = mfma16(fc[qq][1], w0h[1][t], acc);
#pragma unroll
                for (int r = 0; r < 4; ++r) {
                    float y = fmaxf(fmaf(acc[r] + s0q[t], scl[0][t], shf[0][t]), 0.f);
                    sl[(h * 4 + r) * 72 + t * 16 + i] = f2bfu(y);
                }
            }
        }
        LDS_FENCE();

        // ---- L2 phase: read all tiles first, then compute+write in place ----
        bf16x8 x2[4][2];
#pragma unroll
        for (int qq = 0; qq < 4; ++qq) {
            const unsigned short* sl = slab[wid][qq];
            x2[qq][0] = *(const bf16x8*)(sl + i * 72 + h * 8);
            x2[qq][1] = *(const bf16x8*)(sl + i * 72 + h * 8 + 32);
        }
#pragma unroll
        for (int qq = 0; qq < 4; ++qq) {
            unsigned short* sl = slab[wid][qq];
#pragma unroll
            for (int t = 0; t < 4; ++t) {
                f32x4 acc = {0.f, 0.f, 0.f, 0.f};
                acc = mfma16(x2[qq][0], w1r[0][t], acc);
                acc = mfma16(x2[qq][1], w1r[1][t], acc);
#pragma unroll
                for (int r = 0; r < 4; ++r) {
                    float y = fmaxf(fmaf(acc[r], scl[1][t], shf[1][t]), 0.f);
                    sl[(h * 4 + r) * 72 + t * 16 + i] = f2bfu(y);
                }
            }
        }
        LDS_FENCE();

        // ---- L3 phase: read, MFMA, relu-sum, cross-lane reduce ----
        bf16x8 x3[4][2];
#pragma unroll
        for (int qq = 0; qq < 4; ++qq) {
            const unsigned short* sl = slab[wid][qq];
            x3[qq][0] = *(const bf16x8*)(sl + i * 72 + h * 8);
            x3[qq][1] = *(const bf16x8*)(sl + i * 72 + h * 8 + 32);
        }
#pragma unroll
        for (int qq = 0; qq < 4; ++qq) {
#pragma unroll
            for (int t = 0; t < 4; ++t) {
                f32x4 acc = {0.f, 0.f, 0.f, 0.f};
                acc = mfma16(x3[qq][0], w2r[0][t], acc);
                acc = mfma16(x3[qq][1], w2r[1][t], acc);
                float s = 0.f;
#pragma unroll
                for (int r = 0; r < 4; ++r)
                    s += fmaxf(fmaf(acc[r], scl[2][t], shf[2][t]), 0.f);
                s += __shfl_xor(s, 16, 64);  // reduce over h-groups (same i)
                s += __shfl_xor(s, 32, 64);
                if (h == 0) ftsbuf[wid][qb + qq][t * 16 + i] = s * (1.f / 16.f);
            }
        }
        LDS_FENCE();  // slab WAR for next group + ftsbuf visibility
    }

    // ---- shortcut GEMM + epilogue: rows 0..7 = this wave's 8 points ----
    {
        const bf16x8* __restrict__ WS = (const bf16x8*)(wsf + 16384);
        float sscl[4], sshf[4];
#pragma unroll
        for (int t = 0; t < 4; ++t) {
            sscl[t] = bnp[384 + t * 16 + i];
            sshf[t] = bnp[448 + t * 16 + i];
        }
        const unsigned short* fp = fbf + (size_t)(p0 + (i & 7)) * NC;
        bf16x8 a0 = *(const bf16x8*)(fp + 8 * h);
        bf16x8 a1 = *(const bf16x8*)(fp + 32 + 8 * h);
#pragma unroll
        for (int t = 0; t < 4; ++t) {
            f32x4 acc = {0.f, 0.f, 0.f, 0.f};
            acc = mfma16(a0, WS[t * 64 + l], acc);
            acc = mfma16(a1, WS[(4 + t) * 64 + l], acc);
            if (h < 2) {   // C rows 0..7 = real points; 8..15 are duplicates
#pragma unroll
                for (int r = 0; r < 4; ++r) {
                    const int q = h * 4 + r;
                    out[(size_t)(p0 + q) * NC + t * 16 + i] =
                        fmaxf(fmaf(acc[r], sscl[t], sshf[t]) + ftsbuf[wid][q][t * 16 + i], 0.f);
                }
            }
        }
    }
}

extern "C" void kernel_launch(void* const* d_in, const int* in_sizes, int n_in,
                              void* d_out, int out_size, void* d_ws, size_t ws_size,
                              hipStream_t stream) {
    const float* points    = (const float*)d_in[0];
    const float* features  = (const float*)d_in[1];
    const float* w0        = (const float*)d_in[2];
    const float* w1        = (const float*)d_in[3];
    const float* w2        = (const float*)d_in[4];
    const float* gammas    = (const float*)d_in[5];
    const float* betas     = (const float*)d_in[6];
    const float* means     = (const float*)d_in[7];
    const float* variances = (const float*)d_in[8];
    const float* sc_w      = (const float*)d_in[9];
    const float* sc_gamma  = (const float*)d_in[10];
    const float* sc_beta   = (const float*)d_in[11];
    const float* sc_mean   = (const float*)d_in[12];
    const float* sc_var    = (const float*)d_in[13];
    float* out = (float*)d_out;

    int* knn_buf = (int*)d_ws;                                          // 2 MB
    unsigned short* fbf = (unsigned short*)((char*)d_ws + (1 << 21));   // 4 MB
    unsigned short* wsf = (unsigned short*)((char*)d_ws + (3 << 21));   // 40 KB
    float* bnp = (float*)((char*)d_ws + (3 << 21) + 40960);             // 2 KB

    prep_kernel<<<81, 256, 0, stream>>>(w0, w1, w2, sc_w, gammas, betas, means,
                                        variances, sc_gamma, sc_beta, sc_mean,
                                        sc_var, wsf, bnp);
    fcvt_kernel<<<1024, 256, 0, stream>>>(features, fbf);
    knn_kernel<<<NBATCH * 2, 256, 0, stream>>>(points, knn_buf);
    edge_kernel<<<NBATCH * NP / 16, 128, 0, stream>>>(fbf, knn_buf, wsf, bnp, out);
}

// Round 11
// 52.701 us; speedup vs baseline: 1.4890x; 1.4890x over previous
//
#include <hip/hip_runtime.h>
#include <math.h>

#define NBATCH 128
#define NP 256
#define NC 64
#define KNN 16
#define EPSV 1e-3f

typedef __bf16 bf16_t;
typedef bf16_t bf16x8 __attribute__((ext_vector_type(8)));
typedef float f32x4 __attribute__((ext_vector_type(4)));
typedef unsigned short u16x4 __attribute__((ext_vector_type(4)));

static __device__ __forceinline__ f32x4 mfma16(bf16x8 a, bf16x8 b, f32x4 c) {
    return __builtin_amdgcn_mfma_f32_16x16x32_bf16(a, b, c, 0, 0, 0);
}
static __device__ __forceinline__ unsigned short f2bfu(float f) {
    union { bf16_t b; unsigned short u; } cv; cv.b = (bf16_t)f; return cv.u;
}
static __device__ __forceinline__ unsigned umin2(unsigned a, unsigned b) { return a < b ? a : b; }
static __device__ __forceinline__ unsigned umax2(unsigned a, unsigned b) { return a > b ? a : b; }

// Compiler-only ordering fence. All LDS traffic in edge_kernel is wave-private
// and the DS pipe executes a wave's LDS ops in program order, so no HW drain
// (lgkmcnt) is needed — only prevention of compiler reordering. Zero instrs.
#define CFENCE() asm volatile("" ::: "memory")

// Sorted-ascending insert, med3 form: since bk[i-1] <= bk[i],
// new bk[i] = min(max(key, bk[i-1]), bk[i])  (= v_med3_u32). 2 ops/level.
#define INSERTK(k_)                                                   \
    do {                                                              \
        _Pragma("unroll")                                             \
        for (int ii = KNN - 1; ii >= 1; --ii)                         \
            bk[ii] = umin2(umax2((k_), bk[ii - 1]), bk[ii]);          \
        bk[0] = umin2((k_), bk[0]);                                   \
    } while (0)

// ---------------------------------------------------------------------------
// kNN: packed u32 (dist|idx) keys, f32 cancellation-free distances, 2-way
// candidate split, med3 insertion. Grid = 2*NBATCH blocks of 256 thr.
// ---------------------------------------------------------------------------
__global__ __launch_bounds__(256) void knn_kernel(const float* __restrict__ points,
                                                  int* __restrict__ idx_out) {
    const int bb = blockIdx.x >> 1;
    const int qbase = (blockIdx.x & 1) * 128;
    const int t = threadIdx.x;
    const int qt = t & 127;
    const int half = t >> 7;
    const int p = qbase + qt;            // my query (within batch)

    __shared__ __align__(16) float4 sp[NP];
    __shared__ unsigned sk[128][17];

    const float* pb = points + (size_t)bb * NP * 3;
    sp[t] = make_float4(pb[t * 3 + 0], pb[t * 3 + 1], pb[t * 3 + 2], 0.f);
    __syncthreads();

    const float4 qp = sp[p];
    unsigned bk[KNN];
#pragma unroll
    for (int i = 0; i < KNN; ++i) bk[i] = 0xFFFFFFFFu;

    const int cbase = half * 128;        // wave-uniform
#pragma unroll 4
    for (int c = 0; c < 128; ++c) {
        const int cand = cbase + c;
        const float4 P = sp[cand];       // wave-uniform addr -> LDS broadcast
        const float dx = qp.x - P.x, dy = qp.y - P.y, dz = qp.z - P.z;
        const float d = fmaf(dx, dx, fmaf(dy, dy, dz * dz));
        unsigned key = (__float_as_uint(d) & 0xFFFFFF00u) | (unsigned)cand;
        key = (cand == p) ? 0xFFFFFFFFu : key;   // self-exclusion, branchless
        INSERTK(key);
    }

    if (half == 1) {
#pragma unroll
        for (int i = 0; i < KNN; ++i) sk[qt][i] = bk[i];
    }
    __syncthreads();
    if (half == 0) {
        for (int j = 0; j < KNN; ++j) {
            const unsigned key = sk[qt][j];
            if (key >= bk[KNN - 1]) break;   // ascending -> rest can't qualify
            INSERTK(key);
        }
        int* op = idx_out + ((size_t)bb * NP + p) * KNN;
#pragma unroll
        for (int i = 0; i < KNN; ++i) op[i] = (int)(bk[i] & 0xFFu);
    }
}

// ---------------------------------------------------------------------------
// fcvt: features f32 -> bf16 once.
// ---------------------------------------------------------------------------
__global__ __launch_bounds__(256) void fcvt_kernel(const float* __restrict__ f,
                                                   unsigned short* __restrict__ o) {
    const int tid = blockIdx.x * 256 + threadIdx.x;
    const float4 a = ((const float4*)f)[tid * 2];
    const float4 b = ((const float4*)f)[tid * 2 + 1];
    union { unsigned short s[8]; uint4 v; } r;
    r.s[0] = f2bfu(a.x); r.s[1] = f2bfu(a.y); r.s[2] = f2bfu(a.z); r.s[3] = f2bfu(a.w);
    r.s[4] = f2bfu(b.x); r.s[5] = f2bfu(b.y); r.s[6] = f2bfu(b.z); r.s[7] = f2bfu(b.w);
    ((uint4*)o)[tid] = r.v;
}

// ---------------------------------------------------------------------------
// Prep: weights in MFMA B-fragment order (bf16) + folded BN params.
// CHANNEL PERMUTATION: frag col-idx (t*16+i) carries CHANNEL 4i+t, so a
// lane's 4 C-frag outputs per row are contiguous channels -> b64 LDS writes.
// Input rows (K) stay identity (slab position = channel).
// wsf regions (u16 offsets), 8 frags each:
//   V [0,4096) = w0lo-w0hi ; w0hi [4096,8192) ; w1 [8192,12288) ;
//   w2 [12288,16384) ; ws [16384,20480)
// bnp: scl[192], shf[192], sscl[64], sshf[64]  (channel-indexed).
// ---------------------------------------------------------------------------
__global__ __launch_bounds__(256) void prep_kernel(
    const float* __restrict__ w0, const float* __restrict__ w1,
    const float* __restrict__ w2, const float* __restrict__ sc_w,
    const float* __restrict__ gammas, const float* __restrict__ betas,
    const float* __restrict__ means, const float* __restrict__ variances,
    const float* __restrict__ sc_gamma, const float* __restrict__ sc_beta,
    const float* __restrict__ sc_mean, const float* __restrict__ sc_var,
    unsigned short* __restrict__ wsf, float* __restrict__ bnp)
{
    const int tid = blockIdx.x * 256 + threadIdx.x;
    if (tid < 20480) {
        const int region = tid >> 12;          // 0:V 1:w0hi 2:w1 3:w2 4:ws
        const int e2 = tid & 4095;
        const int f = e2 >> 9;                 // frag 0..7
        const int r = e2 & 511;
        const int lane = r >> 3, j = r & 7;
        const int ks = f >> 2, t = f & 3;
        const int row = ks * 32 + (lane >> 4) * 8 + j;
        const int col = 4 * (lane & 15) + t;   // PERMUTED output channel
        float v;
        if (region == 0)      v = w0[row * 64 + col] - w0[(64 + row) * 64 + col];
        else if (region == 1) v = w0[(64 + row) * 64 + col];
        else if (region == 2) v = w1[row * 64 + col];
        else if (region == 3) v = w2[row * 64 + col];
        else                  v = sc_w[row * 64 + col];
        wsf[tid] = f2bfu(v);
    } else {
        const int e = tid - 20480;
        if (e < 192) {
            float s = gammas[e] * rsqrtf(variances[e] + EPSV);
            bnp[e] = s;
            bnp[192 + e] = betas[e] - means[e] * s;
        } else if (e < 256) {
            const int d = e - 192;
            float s = sc_gamma[d] * rsqrtf(sc_var[d] + EPSV);
            bnp[384 + d] = s;
            bnp[448 + d] = sc_beta[d] - sc_mean[d] * s;
        }
    }
}

// ---------------------------------------------------------------------------
// Edge MLP v7: R9 structure (4 independent waves/WG, wave = 8 points, no
// __syncthreads) + channel permutation (b64 slab writes, float4 param/s0/fts/
// out accesses) + compiler-only fences (no lgkmcnt drains; per-wave DS pipe
// is in-order and all LDS is wave-private). Single in-place slab per wave.
// ---------------------------------------------------------------------------
__global__ __launch_bounds__(256) void edge_kernel(
    const unsigned short* __restrict__ fbf, const int* __restrict__ knn_idx,
    const unsigned short* __restrict__ wsf, const float* __restrict__ bnp,
    float* __restrict__ out)
{
    __shared__ __align__(16) unsigned short slab[4][16 * 72];  // 9.2 KB
    __shared__ __align__(16) float s0buf[4][8][64];            // 8 KB
    __shared__ __align__(16) float ftsbuf[4][8][64];           // 8 KB

    const int tid = threadIdx.x;
    const int wid = tid >> 6;
    const int l = tid & 63;
    const int i = l & 15;
    const int h = l >> 4;
    // bijective XCD swizzle: 1024 blocks = 8 XCDs x 128 contiguous work items
    const int wg = (blockIdx.x & 7) * 128 + (blockIdx.x >> 3);
    const int p0 = (wg * 4 + wid) * 8;
    const int b = p0 >> 8;

    unsigned short* sl = slab[wid];

    const bf16x8* __restrict__ WV = (const bf16x8*)(wsf);
    const bf16x8* __restrict__ W0H = (const bf16x8*)(wsf + 4096);
    const bf16x8* __restrict__ W1 = (const bf16x8*)(wsf + 8192);
    const bf16x8* __restrict__ W2 = (const bf16x8*)(wsf + 12288);

    // main-loop weights resident in registers (24 frags = 96 VGPR)
    bf16x8 w0h[2][4], w1r[2][4], w2r[2][4];
#pragma unroll
    for (int ks = 0; ks < 2; ++ks)
#pragma unroll
        for (int t = 0; t < 4; ++t) {
            w0h[ks][t] = W0H[(ks * 4 + t) * 64 + l];
            w1r[ks][t] = W1[(ks * 4 + t) * 64 + l];
            w2r[ks][t] = W2[(ks * 4 + t) * 64 + l];
        }

    // BN params: lane's channels are 4i..4i+3 -> float4 loads
    float4 scl[3], shf[3];
#pragma unroll
    for (int L = 0; L < 3; ++L) {
        scl[L] = *(const float4*)&bnp[L * 64 + 4 * i];
        shf[L] = *(const float4*)&bnp[192 + L * 64 + 4 * i];
    }

    // ---- prologue: s0 = ctr @ V for this wave's 8 points (rows 8..15 dup) ----
    {
        const unsigned short* cp = fbf + (size_t)(p0 + (i & 7)) * NC;
        bf16x8 a0 = *(const bf16x8*)(cp + 8 * h);
        bf16x8 a1 = *(const bf16x8*)(cp + 32 + 8 * h);
        f32x4 acc[4];
#pragma unroll
        for (int t = 0; t < 4; ++t) {
            f32x4 z = {0.f, 0.f, 0.f, 0.f};
            z = mfma16(a0, WV[t * 64 + l], z);
            acc[t] = mfma16(a1, WV[(4 + t) * 64 + l], z);
        }
        if (h < 2) {
#pragma unroll
            for (int r = 0; r < 4; ++r) {
                float4 v = make_float4(acc[0][r], acc[1][r], acc[2][r], acc[3][r]);
                *(float4*)&s0buf[wid][h * 4 + r][4 * i] = v;
            }
        }
    }
    int nks[8];
#pragma unroll
    for (int q = 0; q < 8; ++q) nks[q] = knn_idx[(size_t)(p0 + q) * KNN + i];
    CFENCE();  // s0buf visible before L1 reads (cross-lane, same wave)

    // prime point 0's neighbor A-fragments
    bf16x8 fc0, fc1;
    {
        const unsigned short* sp = fbf + (size_t)(b * NP + nks[0]) * NC;
        fc0 = *(const bf16x8*)(sp + 8 * h);
        fc1 = *(const bf16x8*)(sp + 32 + 8 * h);
    }

#pragma unroll
    for (int q = 0; q < 8; ++q) {
        // ---- layer 1: nbr @ w0hi + s0 -> slab (4x ds_write_b64) ----
        float4 s0q = *(const float4*)&s0buf[wid][q][4 * i];
        {
            f32x4 acc[4];
#pragma unroll
            for (int t = 0; t < 4; ++t) {
                f32x4 z = {0.f, 0.f, 0.f, 0.f};
                z = mfma16(fc0, w0h[0][t], z);
                acc[t] = mfma16(fc1, w0h[1][t], z);
            }
            const float* sp_ = (const float*)&s0q;
            const float* sc_ = (const float*)&scl[0];
            const float* sh_ = (const float*)&shf[0];
#pragma unroll
            for (int r = 0; r < 4; ++r) {
                u16x4 pk;
#pragma unroll
                for (int t = 0; t < 4; ++t)
                    pk[t] = f2bfu(fmaxf(fmaf(acc[t][r] + sp_[t], sc_[t], sh_[t]), 0.f));
                *(u16x4*)&sl[(h * 4 + r) * 72 + 4 * i] = pk;
            }
        }
        // prefetch next point's fragments (global loads stay ahead of fences)
        bf16x8 fn0, fn1;
        if (q < 7) {
            const unsigned short* sp = fbf + (size_t)(b * NP + nks[(q + 1) & 7]) * NC;
            fn0 = *(const bf16x8*)(sp + 8 * h);
            fn1 = *(const bf16x8*)(sp + 32 + 8 * h);
        }
        CFENCE();  // L1 writes ordered before L2 reads

        // ---- layer 2 (in-place: reads all issued before writes by dataflow) ----
        {
            bf16x8 x0 = *(const bf16x8*)(sl + i * 72 + h * 8);
            bf16x8 x1 = *(const bf16x8*)(sl + i * 72 + h * 8 + 32);
            f32x4 acc[4];
#pragma unroll
            for (int t = 0; t < 4; ++t) {
                f32x4 z = {0.f, 0.f, 0.f, 0.f};
                z = mfma16(x0, w1r[0][t], z);
                acc[t] = mfma16(x1, w1r[1][t], z);
            }
            const float* sc_ = (const float*)&scl[1];
            const float* sh_ = (const float*)&shf[1];
#pragma unroll
            for (int r = 0; r < 4; ++r) {
                u16x4 pk;
#pragma unroll
                for (int t = 0; t < 4; ++t)
                    pk[t] = f2bfu(fmaxf(fmaf(acc[t][r], sc_[t], sh_[t]), 0.f));
                *(u16x4*)&sl[(h * 4 + r) * 72 + 4 * i] = pk;
            }
        }
        CFENCE();  // L2 writes ordered before L3 reads

        // ---- layer 3 + mean over k -> ftsbuf ----
        {
            bf16x8 x0 = *(const bf16x8*)(sl + i * 72 + h * 8);
            bf16x8 x1 = *(const bf16x8*)(sl + i * 72 + h * 8 + 32);
            const float* sc_ = (const float*)&scl[2];
            const float* sh_ = (const float*)&shf[2];
            float st[4];
#pragma unroll
            for (int t = 0; t < 4; ++t) {
                f32x4 z = {0.f, 0.f, 0.f, 0.f};
                z = mfma16(x0, w2r[0][t], z);
                f32x4 acc = mfma16(x1, w2r[1][t], z);
                float s = 0.f;
#pragma unroll
                for (int r = 0; r < 4; ++r)
                    s += fmaxf(fmaf(acc[r], sc_[t], sh_[t]), 0.f);
                s += __shfl_xor(s, 16, 64);
                s += __shfl_xor(s, 32, 64);
                st[t] = s * (1.f / 16.f);
            }
            if (h == 0)
                *(float4*)&ftsbuf[wid][q][4 * i] =
                    make_float4(st[0], st[1], st[2], st[3]);
        }
        CFENCE();  // L3 reads ordered before next point's L1 writes (WAR)
        fc0 = fn0; fc1 = fn1;
    }

    // ---- shortcut GEMM + epilogue ----
    {
        const bf16x8* __restrict__ WS = (const bf16x8*)(wsf + 16384);
        float4 sscl = *(const float4*)&bnp[384 + 4 * i];
        float4 sshf = *(const float4*)&bnp[448 + 4 * i];
        const unsigned short* fp = fbf + (size_t)(p0 + (i & 7)) * NC;
        bf16x8 a0 = *(const bf16x8*)(fp + 8 * h);
        bf16x8 a1 = *(const bf16x8*)(fp + 32 + 8 * h);
        f32x4 acc[4];
#pragma unroll
        for (int t = 0; t < 4; ++t) {
            f32x4 z = {0.f, 0.f, 0.f, 0.f};
            z = mfma16(a0, WS[t * 64 + l], z);
            acc[t] = mfma16(a1, WS[(4 + t) * 64 + l], z);
        }
        if (h < 2) {
            const float* ss_ = (const float*)&sscl;
            const float* sf_ = (const float*)&sshf;
#pragma unroll
            for (int r = 0; r < 4; ++r) {
                const int q = h * 4 + r;
                float4 fts = *(const float4*)&ftsbuf[wid][q][4 * i];
                const float* ft_ = (const float*)&fts;
                float4 o;
                float* o_ = (float*)&o;
#pragma unroll
                for (int t = 0; t < 4; ++t)
                    o_[t] = fmaxf(fmaf(acc[t][r], ss_[t], sf_[t]) + ft_[t], 0.f);
                *(float4*)&out[(size_t)(p0 + q) * NC + 4 * i] = o;
            }
        }
    }
}

extern "C" void kernel_launch(void* const* d_in, const int* in_sizes, int n_in,
                              void* d_out, int out_size, void* d_ws, size_t ws_size,
                              hipStream_t stream) {
    const float* points    = (const float*)d_in[0];
    const float* features  = (const float*)d_in[1];
    const float* w0        = (const float*)d_in[2];
    const float* w1        = (const float*)d_in[3];
    const float* w2        = (const float*)d_in[4];
    const float* gammas    = (const float*)d_in[5];
    const float* betas     = (const float*)d_in[6];
    const float* means     = (const float*)d_in[7];
    const float* variances = (const float*)d_in[8];
    const float* sc_w      = (const float*)d_in[9];
    const float* sc_gamma  = (const float*)d_in[10];
    const float* sc_beta   = (const float*)d_in[11];
    const float* sc_mean   = (const float*)d_in[12];
    const float* sc_var    = (const float*)d_in[13];
    float* out = (float*)d_out;

    int* knn_buf = (int*)d_ws;                                          // 2 MB
    unsigned short* fbf = (unsigned short*)((char*)d_ws + (1 << 21));   // 4 MB
    unsigned short* wsf = (unsigned short*)((char*)d_ws + (3 << 21));   // 40 KB
    float* bnp = (float*)((char*)d_ws + (3 << 21) + 40960);             // 2 KB

    prep_kernel<<<81, 256, 0, stream>>>(w0, w1, w2, sc_w, gammas, betas, means,
                                        variances, sc_gamma, sc_beta, sc_mean,
                                        sc_var, wsf, bnp);
    fcvt_kernel<<<1024, 256, 0, stream>>>(features, fbf);
    knn_kernel<<<NBATCH * 2, 256, 0, stream>>>(points, knn_buf);
    edge_kernel<<<NBATCH * NP / 32, 256, 0, stream>>>(fbf, knn_buf, wsf, bnp, out);
}

// Round 12
// 48.404 us; speedup vs baseline: 1.6212x; 1.0888x over previous
//
#include <hip/hip_runtime.h>
#include <math.h>

#define NBATCH 128
#define NP 256
#define NC 64
#define KNN 16
#define EPSV 1e-3f

typedef __bf16 bf16_t;
typedef bf16_t bf16x8 __attribute__((ext_vector_type(8)));
typedef float f32x4 __attribute__((ext_vector_type(4)));
typedef unsigned short u16x4 __attribute__((ext_vector_type(4)));

static __device__ __forceinline__ f32x4 mfma16(bf16x8 a, bf16x8 b, f32x4 c) {
    return __builtin_amdgcn_mfma_f32_16x16x32_bf16(a, b, c, 0, 0, 0);
}
static __device__ __forceinline__ unsigned short f2bfu(float f) {
    union { bf16_t b; unsigned short u; } cv; cv.b = (bf16_t)f; return cv.u;
}
static __device__ __forceinline__ unsigned umin2(unsigned a, unsigned b) { return a < b ? a : b; }
static __device__ __forceinline__ unsigned umax2(unsigned a, unsigned b) { return a > b ? a : b; }

// Compiler-only ordering fence (R11-validated): all edge LDS is wave-private
// and the per-wave DS pipe is in-order, so no HW drain needed. Zero instrs.
#define CFENCE() asm volatile("" ::: "memory")

// Sorted-ascending insert, med3 form (2 ops/level, levels independent).
#define INSERTK(k_)                                                   \
    do {                                                              \
        _Pragma("unroll")                                             \
        for (int ii = KNN - 1; ii >= 1; --ii)                         \
            bk[ii] = umin2(umax2((k_), bk[ii - 1]), bk[ii]);          \
        bk[0] = umin2((k_), bk[0]);                                   \
    } while (0)

// ---------------------------------------------------------------------------
// setup_kernel: fused fcvt + prep + knn (mutually independent work, one
// dispatch instead of three -> kills 2 launch gaps).
//   blocks [0,1024)    : fcvt  — features f32 -> bf16
//   blocks [1024,1105) : prep  — weight B-frags (channel-permuted) + BN fold
//   blocks [1105,1361) : knn   — packed-key 2-way split kNN
// ---------------------------------------------------------------------------
__global__ __launch_bounds__(256) void setup_kernel(
    const float* __restrict__ points, const float* __restrict__ features,
    const float* __restrict__ w0, const float* __restrict__ w1,
    const float* __restrict__ w2, const float* __restrict__ sc_w,
    const float* __restrict__ gammas, const float* __restrict__ betas,
    const float* __restrict__ means, const float* __restrict__ variances,
    const float* __restrict__ sc_gamma, const float* __restrict__ sc_beta,
    const float* __restrict__ sc_mean, const float* __restrict__ sc_var,
    unsigned short* __restrict__ fbf, unsigned short* __restrict__ wsf,
    float* __restrict__ bnp, int* __restrict__ knn_out)
{
    const int bid = blockIdx.x;
    if (bid < 1024) {
        // ---- fcvt section ----
        const int tid = bid * 256 + threadIdx.x;
        const float4 a = ((const float4*)features)[tid * 2];
        const float4 b = ((const float4*)features)[tid * 2 + 1];
        union { unsigned short s[8]; uint4 v; } r;
        r.s[0] = f2bfu(a.x); r.s[1] = f2bfu(a.y); r.s[2] = f2bfu(a.z); r.s[3] = f2bfu(a.w);
        r.s[4] = f2bfu(b.x); r.s[5] = f2bfu(b.y); r.s[6] = f2bfu(b.z); r.s[7] = f2bfu(b.w);
        ((uint4*)fbf)[tid] = r.v;
    } else if (bid < 1105) {
        // ---- prep section: channel-permuted B-frags ----
        // frag col t*16+i carries channel 4i+t (lane's outputs contiguous).
        const int tid = (bid - 1024) * 256 + threadIdx.x;
        if (tid < 20480) {
            const int region = tid >> 12;          // 0:V 1:w0hi 2:w1 3:w2 4:ws
            const int e2 = tid & 4095;
            const int f = e2 >> 9;
            const int r = e2 & 511;
            const int lane = r >> 3, j = r & 7;
            const int ks = f >> 2, t = f & 3;
            const int row = ks * 32 + (lane >> 4) * 8 + j;
            const int col = 4 * (lane & 15) + t;   // PERMUTED output channel
            float v;
            if (region == 0)      v = w0[row * 64 + col] - w0[(64 + row) * 64 + col];
            else if (region == 1) v = w0[(64 + row) * 64 + col];
            else if (region == 2) v = w1[row * 64 + col];
            else if (region == 3) v = w2[row * 64 + col];
            else                  v = sc_w[row * 64 + col];
            wsf[tid] = f2bfu(v);
        } else {
            const int e = tid - 20480;
            if (e < 192) {
                float s = gammas[e] * rsqrtf(variances[e] + EPSV);
                bnp[e] = s;
                bnp[192 + e] = betas[e] - means[e] * s;
            } else if (e < 256) {
                const int d = e - 192;
                float s = sc_gamma[d] * rsqrtf(sc_var[d] + EPSV);
                bnp[384 + d] = s;
                bnp[448 + d] = sc_beta[d] - sc_mean[d] * s;
            }
        }
    } else {
        // ---- knn section ----
        __shared__ __align__(16) float4 sp[NP];
        __shared__ unsigned sk[128][17];
        const int kb = bid - 1105;
        const int bb = kb >> 1;
        const int qbase = (kb & 1) * 128;
        const int t = threadIdx.x;
        const int qt = t & 127;
        const int half = t >> 7;
        const int p = qbase + qt;

        const float* pb = points + (size_t)bb * NP * 3;
        sp[t] = make_float4(pb[t * 3 + 0], pb[t * 3 + 1], pb[t * 3 + 2], 0.f);
        __syncthreads();

        const float4 qp = sp[p];
        unsigned bk[KNN];
#pragma unroll
        for (int i = 0; i < KNN; ++i) bk[i] = 0xFFFFFFFFu;

        const int cbase = half * 128;
#pragma unroll 4
        for (int c = 0; c < 128; ++c) {
            const int cand = cbase + c;
            const float4 P = sp[cand];
            const float dx = qp.x - P.x, dy = qp.y - P.y, dz = qp.z - P.z;
            const float d = fmaf(dx, dx, fmaf(dy, dy, dz * dz));
            unsigned key = (__float_as_uint(d) & 0xFFFFFF00u) | (unsigned)cand;
            key = (cand == p) ? 0xFFFFFFFFu : key;
            INSERTK(key);
        }

        if (half == 1) {
#pragma unroll
            for (int i = 0; i < KNN; ++i) sk[qt][i] = bk[i];
        }
        __syncthreads();
        if (half == 0) {
            for (int j = 0; j < KNN; ++j) {
                const unsigned key = sk[qt][j];
                if (key >= bk[KNN - 1]) break;
                INSERTK(key);
            }
            int* op = knn_out + ((size_t)bb * NP + p) * KNN;
#pragma unroll
            for (int i = 0; i < KNN; ++i) op[i] = (int)(bk[i] & 0xFFu);
        }
    }
}

// ---------------------------------------------------------------------------
// Edge MLP v8: R11 (channel permutation, compiler-only fences, 4 indep
// waves/WG) + 2-point chain pairing: points (2k,2k+1) share each layer phase
// with separate slabs — independent instruction chains between free fences
// let the scheduler overlap chain B's MFMAs with chain A's DS latency.
// ---------------------------------------------------------------------------
__global__ __launch_bounds__(256) void edge_kernel(
    const unsigned short* __restrict__ fbf, const int* __restrict__ knn_idx,
    const unsigned short* __restrict__ wsf, const float* __restrict__ bnp,
    float* __restrict__ out)
{
    __shared__ __align__(16) unsigned short slab[4][2][16 * 72];  // 18.4 KB
    __shared__ __align__(16) float s0buf[4][8][64];               // 8 KB
    __shared__ __align__(16) float ftsbuf[4][8][64];              // 8 KB

    const int tid = threadIdx.x;
    const int wid = tid >> 6;
    const int l = tid & 63;
    const int i = l & 15;
    const int h = l >> 4;
    // bijective XCD swizzle: 1024 blocks = 8 XCDs x 128 contiguous work items
    const int wg = (blockIdx.x & 7) * 128 + (blockIdx.x >> 3);
    const int p0 = (wg * 4 + wid) * 8;
    const int b = p0 >> 8;

    unsigned short* sl0 = slab[wid][0];
    unsigned short* sl1 = slab[wid][1];

    const bf16x8* __restrict__ WV = (const bf16x8*)(wsf);
    const bf16x8* __restrict__ W0H = (const bf16x8*)(wsf + 4096);
    const bf16x8* __restrict__ W1 = (const bf16x8*)(wsf + 8192);
    const bf16x8* __restrict__ W2 = (const bf16x8*)(wsf + 12288);

    // main-loop weights resident in registers (24 frags = 96 VGPR)
    bf16x8 w0h[2][4], w1r[2][4], w2r[2][4];
#pragma unroll
    for (int ks = 0; ks < 2; ++ks)
#pragma unroll
        for (int t = 0; t < 4; ++t) {
            w0h[ks][t] = W0H[(ks * 4 + t) * 64 + l];
            w1r[ks][t] = W1[(ks * 4 + t) * 64 + l];
            w2r[ks][t] = W2[(ks * 4 + t) * 64 + l];
        }

    // BN params: lane's channels are 4i..4i+3 -> float4 loads
    float4 scl[3], shf[3];
#pragma unroll
    for (int L = 0; L < 3; ++L) {
        scl[L] = *(const float4*)&bnp[L * 64 + 4 * i];
        shf[L] = *(const float4*)&bnp[192 + L * 64 + 4 * i];
    }

    // ---- prologue: s0 = ctr @ V for this wave's 8 points (rows 8..15 dup) ----
    {
        const unsigned short* cp = fbf + (size_t)(p0 + (i & 7)) * NC;
        bf16x8 a0 = *(const bf16x8*)(cp + 8 * h);
        bf16x8 a1 = *(const bf16x8*)(cp + 32 + 8 * h);
        f32x4 acc[4];
#pragma unroll
        for (int t = 0; t < 4; ++t) {
            f32x4 z = {0.f, 0.f, 0.f, 0.f};
            z = mfma16(a0, WV[t * 64 + l], z);
            acc[t] = mfma16(a1, WV[(4 + t) * 64 + l], z);
        }
        if (h < 2) {
#pragma unroll
            for (int r = 0; r < 4; ++r) {
                float4 v = make_float4(acc[0][r], acc[1][r], acc[2][r], acc[3][r]);
                *(float4*)&s0buf[wid][h * 4 + r][4 * i] = v;
            }
        }
    }
    int nks[8];
#pragma unroll
    for (int q = 0; q < 8; ++q) nks[q] = knn_idx[(size_t)(p0 + q) * KNN + i];
    CFENCE();  // s0buf visible before L1 reads (same wave)

#pragma unroll
    for (int qp = 0; qp < 4; ++qp) {
        const int q0 = 2 * qp, q1 = 2 * qp + 1;
        // ---- gather both points' neighbor fragments ----
        bf16x8 f00, f01, f10, f11;
        {
            const unsigned short* sp0 = fbf + (size_t)(b * NP + nks[q0]) * NC;
            const unsigned short* sp1 = fbf + (size_t)(b * NP + nks[q1]) * NC;
            f00 = *(const bf16x8*)(sp0 + 8 * h);
            f01 = *(const bf16x8*)(sp0 + 32 + 8 * h);
            f10 = *(const bf16x8*)(sp1 + 8 * h);
            f11 = *(const bf16x8*)(sp1 + 32 + 8 * h);
        }
        // ---- L1 phase (chains A,B independent) ----
        {
            float4 s0a = *(const float4*)&s0buf[wid][q0][4 * i];
            const float* sc_ = (const float*)&scl[0];
            const float* sh_ = (const float*)&shf[0];
            f32x4 acc[4];
#pragma unroll
            for (int t = 0; t < 4; ++t) {
                f32x4 z = {0.f, 0.f, 0.f, 0.f};
                z = mfma16(f00, w0h[0][t], z);
                acc[t] = mfma16(f01, w0h[1][t], z);
            }
            const float* sp_ = (const float*)&s0a;
#pragma unroll
            for (int r = 0; r < 4; ++r) {
                u16x4 pk;
#pragma unroll
                for (int t = 0; t < 4; ++t)
                    pk[t] = f2bfu(fmaxf(fmaf(acc[t][r] + sp_[t], sc_[t], sh_[t]), 0.f));
                *(u16x4*)&sl0[(h * 4 + r) * 72 + 4 * i] = pk;
            }
            float4 s0b = *(const float4*)&s0buf[wid][q1][4 * i];
            const float* sq_ = (const float*)&s0b;
#pragma unroll
            for (int t = 0; t < 4; ++t) {
                f32x4 z = {0.f, 0.f, 0.f, 0.f};
                z = mfma16(f10, w0h[0][t], z);
                acc[t] = mfma16(f11, w0h[1][t], z);
            }
#pragma unroll
            for (int r = 0; r < 4; ++r) {
                u16x4 pk;
#pragma unroll
                for (int t = 0; t < 4; ++t)
                    pk[t] = f2bfu(fmaxf(fmaf(acc[t][r] + sq_[t], sc_[t], sh_[t]), 0.f));
                *(u16x4*)&sl1[(h * 4 + r) * 72 + 4 * i] = pk;
            }
        }
        CFENCE();

        // ---- L2 phase (in-place, both chains) ----
        {
            bf16x8 xa0 = *(const bf16x8*)(sl0 + i * 72 + h * 8);
            bf16x8 xa1 = *(const bf16x8*)(sl0 + i * 72 + h * 8 + 32);
            bf16x8 xb0 = *(const bf16x8*)(sl1 + i * 72 + h * 8);
            bf16x8 xb1 = *(const bf16x8*)(sl1 + i * 72 + h * 8 + 32);
            const float* sc_ = (const float*)&scl[1];
            const float* sh_ = (const float*)&shf[1];
            f32x4 acc[4];
#pragma unroll
            for (int t = 0; t < 4; ++t) {
                f32x4 z = {0.f, 0.f, 0.f, 0.f};
                z = mfma16(xa0, w1r[0][t], z);
                acc[t] = mfma16(xa1, w1r[1][t], z);
            }
#pragma unroll
            for (int r = 0; r < 4; ++r) {
                u16x4 pk;
#pragma unroll
                for (int t = 0; t < 4; ++t)
                    pk[t] = f2bfu(fmaxf(fmaf(acc[t][r], sc_[t], sh_[t]), 0.f));
                *(u16x4*)&sl0[(h * 4 + r) * 72 + 4 * i] = pk;
            }
#pragma unroll
            for (int t = 0; t < 4; ++t) {
                f32x4 z = {0.f, 0.f, 0.f, 0.f};
                z = mfma16(xb0, w1r[0][t], z);
                acc[t] = mfma16(xb1, w1r[1][t], z);
            }
#pragma unroll
            for (int r = 0; r < 4; ++r) {
                u16x4 pk;
#pragma unroll
                for (int t = 0; t < 4; ++t)
                    pk[t] = f2bfu(fmaxf(fmaf(acc[t][r], sc_[t], sh_[t]), 0.f));
                *(u16x4*)&sl1[(h * 4 + r) * 72 + 4 * i] = pk;
            }
        }
        CFENCE();

        // ---- L3 phase + mean over k (both chains) ----
        {
            bf16x8 xa0 = *(const bf16x8*)(sl0 + i * 72 + h * 8);
            bf16x8 xa1 = *(const bf16x8*)(sl0 + i * 72 + h * 8 + 32);
            bf16x8 xb0 = *(const bf16x8*)(sl1 + i * 72 + h * 8);
            bf16x8 xb1 = *(const bf16x8*)(sl1 + i * 72 + h * 8 + 32);
            const float* sc_ = (const float*)&scl[2];
            const float* sh_ = (const float*)&shf[2];
            float sa[4], sb[4];
#pragma unroll
            for (int t = 0; t < 4; ++t) {
                f32x4 z = {0.f, 0.f, 0.f, 0.f};
                z = mfma16(xa0, w2r[0][t], z);
                f32x4 acc = mfma16(xa1, w2r[1][t], z);
                float s = 0.f;
#pragma unroll
                for (int r = 0; r < 4; ++r)
                    s += fmaxf(fmaf(acc[r], sc_[t], sh_[t]), 0.f);
                z = (f32x4){0.f, 0.f, 0.f, 0.f};
                z = mfma16(xb0, w2r[0][t], z);
                f32x4 accb = mfma16(xb1, w2r[1][t], z);
                float sB = 0.f;
#pragma unroll
                for (int r = 0; r < 4; ++r)
                    sB += fmaxf(fmaf(accb[r], sc_[t], sh_[t]), 0.f);
                s += __shfl_xor(s, 16, 64);
                s += __shfl_xor(s, 32, 64);
                sB += __shfl_xor(sB, 16, 64);
                sB += __shfl_xor(sB, 32, 64);
                sa[t] = s * (1.f / 16.f);
                sb[t] = sB * (1.f / 16.f);
            }
            if (h == 0) {
                *(float4*)&ftsbuf[wid][q0][4 * i] = make_float4(sa[0], sa[1], sa[2], sa[3]);
                *(float4*)&ftsbuf[wid][q1][4 * i] = make_float4(sb[0], sb[1], sb[2], sb[3]);
            }
        }
        CFENCE();  // WAR before next pair's L1 writes
    }

    // ---- shortcut GEMM + epilogue ----
    {
        const bf16x8* __restrict__ WS = (const bf16x8*)(wsf + 16384);
        float4 sscl = *(const float4*)&bnp[384 + 4 * i];
        float4 sshf = *(const float4*)&bnp[448 + 4 * i];
        const unsigned short* fp = fbf + (size_t)(p0 + (i & 7)) * NC;
        bf16x8 a0 = *(const bf16x8*)(fp + 8 * h);
        bf16x8 a1 = *(const bf16x8*)(fp + 32 + 8 * h);
        f32x4 acc[4];
#pragma unroll
        for (int t = 0; t < 4; ++t) {
            f32x4 z = {0.f, 0.f, 0.f, 0.f};
            z = mfma16(a0, WS[t * 64 + l], z);
            acc[t] = mfma16(a1, WS[(4 + t) * 64 + l], z);
        }
        if (h < 2) {
            const float* ss_ = (const float*)&sscl;
            const float* sf_ = (const float*)&sshf;
#pragma unroll
            for (int r = 0; r < 4; ++r) {
                const int q = h * 4 + r;
                float4 fts = *(const float4*)&ftsbuf[wid][q][4 * i];
                const float* ft_ = (const float*)&fts;
                float4 o;
                float* o_ = (float*)&o;
#pragma unroll
                for (int t = 0; t < 4; ++t)
                    o_[t] = fmaxf(fmaf(acc[t][r], ss_[t], sf_[t]) + ft_[t], 0.f);
                *(float4*)&out[(size_t)(p0 + q) * NC + 4 * i] = o;
            }
        }
    }
}

extern "C" void kernel_launch(void* const* d_in, const int* in_sizes, int n_in,
                              void* d_out, int out_size, void* d_ws, size_t ws_size,
                              hipStream_t stream) {
    const float* points    = (const float*)d_in[0];
    const float* features  = (const float*)d_in[1];
    const float* w0        = (const float*)d_in[2];
    const float* w1        = (const float*)d_in[3];
    const float* w2        = (const float*)d_in[4];
    const float* gammas    = (const float*)d_in[5];
    const float* betas     = (const float*)d_in[6];
    const float* means     = (const float*)d_in[7];
    const float* variances = (const float*)d_in[8];
    const float* sc_w      = (const float*)d_in[9];
    const float* sc_gamma  = (const float*)d_in[10];
    const float* sc_beta   = (const float*)d_in[11];
    const float* sc_mean   = (const float*)d_in[12];
    const float* sc_var    = (const float*)d_in[13];
    float* out = (float*)d_out;

    int* knn_buf = (int*)d_ws;                                          // 2 MB
    unsigned short* fbf = (unsigned short*)((char*)d_ws + (1 << 21));   // 4 MB
    unsigned short* wsf = (unsigned short*)((char*)d_ws + (3 << 21));   // 40 KB
    float* bnp = (float*)((char*)d_ws + (3 << 21) + 40960);             // 2 KB

    setup_kernel<<<1361, 256, 0, stream>>>(points, features, w0, w1, w2, sc_w,
                                           gammas, betas, means, variances,
                                           sc_gamma, sc_beta, sc_mean, sc_var,
                                           fbf, wsf, bnp, knn_buf);
    edge_kernel<<<NBATCH * NP / 32, 256, 0, stream>>>(fbf, knn_buf, wsf, bnp, out);
}

// Round 13
// 46.992 us; speedup vs baseline: 1.6699x; 1.0300x over previous
//
#include <hip/hip_runtime.h>
#include <math.h>

#define NBATCH 128
#define NP 256
#define NC 64
#define KNN 16
#define EPSV 1e-3f

typedef __bf16 bf16_t;
typedef bf16_t bf16x8 __attribute__((ext_vector_type(8)));
typedef float f32x4 __attribute__((ext_vector_type(4)));
typedef unsigned short u16x4 __attribute__((ext_vector_type(4)));

static __device__ __forceinline__ f32x4 mfma16(bf16x8 a, bf16x8 b, f32x4 c) {
    return __builtin_amdgcn_mfma_f32_16x16x32_bf16(a, b, c, 0, 0, 0);
}
static __device__ __forceinline__ unsigned short f2bfu(float f) {
    union { bf16_t b; unsigned short u; } cv; cv.b = (bf16_t)f; return cv.u;
}
static __device__ __forceinline__ unsigned umin2(unsigned a, unsigned b) { return a < b ? a : b; }
static __device__ __forceinline__ unsigned umax2(unsigned a, unsigned b) { return a > b ? a : b; }

// Compiler-only ordering fence (R11-validated): wave-private LDS + in-order
// per-wave DS pipe -> no HW drain needed. Zero instructions.
#define CFENCE() asm volatile("" ::: "memory")

// Sorted-ascending insert, med3 form (2 ops/level, levels independent).
#define INSERTK(k_)                                                   \
    do {                                                              \
        _Pragma("unroll")                                             \
        for (int ii = KNN - 1; ii >= 1; --ii)                         \
            bk[ii] = umin2(umax2((k_), bk[ii - 1]), bk[ii]);          \
        bk[0] = umin2((k_), bk[0]);                                   \
    } while (0)

// ---------------------------------------------------------------------------
// setup_kernel: fused fcvt + prep + knn (one dispatch).
//   blocks [0,1024)    : fcvt  — features f32 -> bf16
//   blocks [1024,1105) : prep  — weight B-frags (channel-permuted) + BN fold
//   blocks [1105,1361) : knn   — packed-key 2-way split kNN
// ---------------------------------------------------------------------------
__global__ __launch_bounds__(256) void setup_kernel(
    const float* __restrict__ points, const float* __restrict__ features,
    const float* __restrict__ w0, const float* __restrict__ w1,
    const float* __restrict__ w2, const float* __restrict__ sc_w,
    const float* __restrict__ gammas, const float* __restrict__ betas,
    const float* __restrict__ means, const float* __restrict__ variances,
    const float* __restrict__ sc_gamma, const float* __restrict__ sc_beta,
    const float* __restrict__ sc_mean, const float* __restrict__ sc_var,
    unsigned short* __restrict__ fbf, unsigned short* __restrict__ wsf,
    float* __restrict__ bnp, int* __restrict__ knn_out)
{
    const int bid = blockIdx.x;
    if (bid < 1024) {
        // ---- fcvt section ----
        const int tid = bid * 256 + threadIdx.x;
        const float4 a = ((const float4*)features)[tid * 2];
        const float4 b = ((const float4*)features)[tid * 2 + 1];
        union { unsigned short s[8]; uint4 v; } r;
        r.s[0] = f2bfu(a.x); r.s[1] = f2bfu(a.y); r.s[2] = f2bfu(a.z); r.s[3] = f2bfu(a.w);
        r.s[4] = f2bfu(b.x); r.s[5] = f2bfu(b.y); r.s[6] = f2bfu(b.z); r.s[7] = f2bfu(b.w);
        ((uint4*)fbf)[tid] = r.v;
    } else if (bid < 1105) {
        // ---- prep section: channel-permuted B-frags ----
        const int tid = (bid - 1024) * 256 + threadIdx.x;
        if (tid < 20480) {
            const int region = tid >> 12;          // 0:V 1:w0hi 2:w1 3:w2 4:ws
            const int e2 = tid & 4095;
            const int f = e2 >> 9;
            const int r = e2 & 511;
            const int lane = r >> 3, j = r & 7;
            const int ks = f >> 2, t = f & 3;
            const int row = ks * 32 + (lane >> 4) * 8 + j;
            const int col = 4 * (lane & 15) + t;   // PERMUTED output channel
            float v;
            if (region == 0)      v = w0[row * 64 + col] - w0[(64 + row) * 64 + col];
            else if (region == 1) v = w0[(64 + row) * 64 + col];
            else if (region == 2) v = w1[row * 64 + col];
            else if (region == 3) v = w2[row * 64 + col];
            else                  v = sc_w[row * 64 + col];
            wsf[tid] = f2bfu(v);
        } else {
            const int e = tid - 20480;
            if (e < 192) {
                float s = gammas[e] * rsqrtf(variances[e] + EPSV);
                bnp[e] = s;
                bnp[192 + e] = betas[e] - means[e] * s;
            } else if (e < 256) {
                const int d = e - 192;
                float s = sc_gamma[d] * rsqrtf(sc_var[d] + EPSV);
                bnp[384 + d] = s;
                bnp[448 + d] = sc_beta[d] - sc_mean[d] * s;
            }
        }
    } else {
        // ---- knn section ----
        __shared__ __align__(16) float4 sp[NP];
        __shared__ unsigned sk[128][17];
        const int kb = bid - 1105;
        const int bb = kb >> 1;
        const int qbase = (kb & 1) * 128;
        const int t = threadIdx.x;
        const int qt = t & 127;
        const int half = t >> 7;
        const int p = qbase + qt;

        const float* pb = points + (size_t)bb * NP * 3;
        sp[t] = make_float4(pb[t * 3 + 0], pb[t * 3 + 1], pb[t * 3 + 2], 0.f);
        __syncthreads();

        const float4 qp = sp[p];
        unsigned bk[KNN];
#pragma unroll
        for (int i = 0; i < KNN; ++i) bk[i] = 0xFFFFFFFFu;

        const int cbase = half * 128;
#pragma unroll 4
        for (int c = 0; c < 128; ++c) {
            const int cand = cbase + c;
            const float4 P = sp[cand];
            const float dx = qp.x - P.x, dy = qp.y - P.y, dz = qp.z - P.z;
            const float d = fmaf(dx, dx, fmaf(dy, dy, dz * dz));
            unsigned key = (__float_as_uint(d) & 0xFFFFFF00u) | (unsigned)cand;
            key = (cand == p) ? 0xFFFFFFFFu : key;
            INSERTK(key);
        }

        if (half == 1) {
#pragma unroll
            for (int i = 0; i < KNN; ++i) sk[qt][i] = bk[i];
        }
        __syncthreads();
        if (half == 0) {
            for (int j = 0; j < KNN; ++j) {
                const unsigned key = sk[qt][j];
                if (key >= bk[KNN - 1]) break;
                INSERTK(key);
            }
            int* op = knn_out + ((size_t)bb * NP + p) * KNN;
#pragma unroll
            for (int i = 0; i < KNN; ++i) op[i] = (int)(bk[i] & 0xFFu);
        }
    }
}

// ---------------------------------------------------------------------------
// Edge MLP v9: weight fragments evicted from registers into WG-SHARED LDS.
// Theory: unified VGPR+AGPR total >128 capped us at 2 waves/SIMD across
// R7-R12 (occupancy ~17%); dropping the 24 weight frags (96 VGPR) from the
// register file should allow 4 waves/SIMD. The 24 KB of frags is loaded once
// per WG cooperatively (single __syncthreads) and shared by all 4 waves;
// per-use ds_read_b128 is conflict-free (linear 16B/lane) and ~12 cy.
// LDS/WG = 24 + 4x6.25 = 49 KB -> 3 WGs/CU = 12 waves/CU target.
// ---------------------------------------------------------------------------
__global__ __launch_bounds__(256) void edge_kernel(
    const unsigned short* __restrict__ fbf, const int* __restrict__ knn_idx,
    const unsigned short* __restrict__ wsf, const float* __restrict__ bnp,
    float* __restrict__ out)
{
    __shared__ __align__(16) unsigned short wlds[24 * 512];       // 24 KB shared frags
    __shared__ __align__(16) unsigned short slab[4][16 * 72];     // 9.2 KB
    __shared__ __align__(16) float s0buf[4][8][64];               // 8 KB
    __shared__ __align__(16) float ftsbuf[4][8][64];              // 8 KB

    const int tid = threadIdx.x;
    const int wid = tid >> 6;
    const int l = tid & 63;
    const int i = l & 15;
    const int h = l >> 4;
    // bijective XCD swizzle: 1024 blocks = 8 XCDs x 128 contiguous work items
    const int wg = (blockIdx.x & 7) * 128 + (blockIdx.x >> 3);
    const int p0 = (wg * 4 + wid) * 8;
    const int b = p0 >> 8;

    unsigned short* sl = slab[wid];

    // ---- cooperative load of main-loop weight frags (w0hi,w1,w2) -> LDS ----
    // source: wsf u16 [4096, 16384) = 12288 u16 = 1536 uint4; 256 thr x 6
    {
        const uint4* src = (const uint4*)(wsf + 4096);
        uint4* dst = (uint4*)wlds;
#pragma unroll
        for (int k = 0; k < 6; ++k) dst[tid + k * 256] = src[tid + k * 256];
    }

    // frag accessors into wlds: w0h frags 0..7, w1 frags 8..15, w2 frags 16..23
    // (frag fi, lane l) -> &wlds[fi*512 + l*8], one ds_read_b128.
    #define WF(fi_) (*(const bf16x8*)&wlds[(fi_) * 512 + l * 8])

    // BN params: lane's channels are 4i..4i+3 -> float4 loads
    float4 scl[3], shf[3];
#pragma unroll
    for (int L = 0; L < 3; ++L) {
        scl[L] = *(const float4*)&bnp[L * 64 + 4 * i];
        shf[L] = *(const float4*)&bnp[192 + L * 64 + 4 * i];
    }

    // ---- prologue: s0 = ctr @ V (V frags from GLOBAL, one-shot) ----
    {
        const bf16x8* __restrict__ WV = (const bf16x8*)(wsf);
        const unsigned short* cp = fbf + (size_t)(p0 + (i & 7)) * NC;
        bf16x8 a0 = *(const bf16x8*)(cp + 8 * h);
        bf16x8 a1 = *(const bf16x8*)(cp + 32 + 8 * h);
        f32x4 acc[4];
#pragma unroll
        for (int t = 0; t < 4; ++t) {
            f32x4 z = {0.f, 0.f, 0.f, 0.f};
            z = mfma16(a0, WV[t * 64 + l], z);
            acc[t] = mfma16(a1, WV[(4 + t) * 64 + l], z);
        }
        if (h < 2) {
#pragma unroll
            for (int r = 0; r < 4; ++r) {
                float4 v = make_float4(acc[0][r], acc[1][r], acc[2][r], acc[3][r]);
                *(float4*)&s0buf[wid][h * 4 + r][4 * i] = v;
            }
        }
    }
    int nks[8];
#pragma unroll
    for (int q = 0; q < 8; ++q) nks[q] = knn_idx[(size_t)(p0 + q) * KNN + i];

    __syncthreads();   // weights visible to all 4 waves (also covers s0buf)

    // prime point 0's neighbor A-fragments
    bf16x8 fc0, fc1;
    {
        const unsigned short* sp = fbf + (size_t)(b * NP + nks[0]) * NC;
        fc0 = *(const bf16x8*)(sp + 8 * h);
        fc1 = *(const bf16x8*)(sp + 32 + 8 * h);
    }

#pragma unroll
    for (int q = 0; q < 8; ++q) {
        // ---- layer 1: nbr @ w0hi + s0 -> slab (4x ds_write_b64) ----
        float4 s0q = *(const float4*)&s0buf[wid][q][4 * i];
        {
            f32x4 acc[4];
#pragma unroll
            for (int t = 0; t < 4; ++t) {
                f32x4 z = {0.f, 0.f, 0.f, 0.f};
                z = mfma16(fc0, WF(t), z);
                acc[t] = mfma16(fc1, WF(4 + t), z);
            }
            const float* sp_ = (const float*)&s0q;
            const float* sc_ = (const float*)&scl[0];
            const float* sh_ = (const float*)&shf[0];
#pragma unroll
            for (int r = 0; r < 4; ++r) {
                u16x4 pk;
#pragma unroll
                for (int t = 0; t < 4; ++t)
                    pk[t] = f2bfu(fmaxf(fmaf(acc[t][r] + sp_[t], sc_[t], sh_[t]), 0.f));
                *(u16x4*)&sl[(h * 4 + r) * 72 + 4 * i] = pk;
            }
        }
        // prefetch next point's fragments (global loads ahead of LDS phases)
        bf16x8 fn0, fn1;
        if (q < 7) {
            const unsigned short* sp = fbf + (size_t)(b * NP + nks[(q + 1) & 7]) * NC;
            fn0 = *(const bf16x8*)(sp + 8 * h);
            fn1 = *(const bf16x8*)(sp + 32 + 8 * h);
        }
        CFENCE();  // L1 writes ordered before L2 reads

        // ---- layer 2 (in-place) ----
        {
            bf16x8 x0 = *(const bf16x8*)(sl + i * 72 + h * 8);
            bf16x8 x1 = *(const bf16x8*)(sl + i * 72 + h * 8 + 32);
            f32x4 acc[4];
#pragma unroll
            for (int t = 0; t < 4; ++t) {
                f32x4 z = {0.f, 0.f, 0.f, 0.f};
                z = mfma16(x0, WF(8 + t), z);
                acc[t] = mfma16(x1, WF(12 + t), z);
            }
            const float* sc_ = (const float*)&scl[1];
            const float* sh_ = (const float*)&shf[1];
#pragma unroll
            for (int r = 0; r < 4; ++r) {
                u16x4 pk;
#pragma unroll
                for (int t = 0; t < 4; ++t)
                    pk[t] = f2bfu(fmaxf(fmaf(acc[t][r], sc_[t], sh_[t]), 0.f));
                *(u16x4*)&sl[(h * 4 + r) * 72 + 4 * i] = pk;
            }
        }
        CFENCE();  // L2 writes ordered before L3 reads

        // ---- layer 3 + mean over k -> ftsbuf ----
        {
            bf16x8 x0 = *(const bf16x8*)(sl + i * 72 + h * 8);
            bf16x8 x1 = *(const bf16x8*)(sl + i * 72 + h * 8 + 32);
            const float* sc_ = (const float*)&scl[2];
            const float* sh_ = (const float*)&shf[2];
            float st[4];
#pragma unroll
            for (int t = 0; t < 4; ++t) {
                f32x4 z = {0.f, 0.f, 0.f, 0.f};
                z = mfma16(x0, WF(16 + t), z);
                f32x4 acc = mfma16(x1, WF(20 + t), z);
                float s = 0.f;
#pragma unroll
                for (int r = 0; r < 4; ++r)
                    s += fmaxf(fmaf(acc[r], sc_[t], sh_[t]), 0.f);
                s += __shfl_xor(s, 16, 64);
                s += __shfl_xor(s, 32, 64);
                st[t] = s * (1.f / 16.f);
            }
            if (h == 0)
                *(float4*)&ftsbuf[wid][q][4 * i] =
                    make_float4(st[0], st[1], st[2], st[3]);
        }
        CFENCE();  // L3 reads ordered before next point's L1 writes (WAR)
        fc0 = fn0; fc1 = fn1;
    }

    // ---- shortcut GEMM + epilogue (WS frags from GLOBAL, one-shot) ----
    {
        const bf16x8* __restrict__ WS = (const bf16x8*)(wsf + 16384);
        float4 sscl = *(const float4*)&bnp[384 + 4 * i];
        float4 sshf = *(const float4*)&bnp[448 + 4 * i];
        const unsigned short* fp = fbf + (size_t)(p0 + (i & 7)) * NC;
        bf16x8 a0 = *(const bf16x8*)(fp + 8 * h);
        bf16x8 a1 = *(const bf16x8*)(fp + 32 + 8 * h);
        f32x4 acc[4];
#pragma unroll
        for (int t = 0; t < 4; ++t) {
            f32x4 z = {0.f, 0.f, 0.f, 0.f};
            z = mfma16(a0, WS[t * 64 + l], z);
            acc[t] = mfma16(a1, WS[(4 + t) * 64 + l], z);
        }
        if (h < 2) {
            const float* ss_ = (const float*)&sscl;
            const float* sf_ = (const float*)&sshf;
#pragma unroll
            for (int r = 0; r < 4; ++r) {
                const int q = h * 4 + r;
                float4 fts = *(const float4*)&ftsbuf[wid][q][4 * i];
                const float* ft_ = (const float*)&fts;
                float4 o;
                float* o_ = (float*)&o;
#pragma unroll
                for (int t = 0; t < 4; ++t)
                    o_[t] = fmaxf(fmaf(acc[t][r], ss_[t], sf_[t]) + ft_[t], 0.f);
                *(float4*)&out[(size_t)(p0 + q) * NC + 4 * i] = o;
            }
        }
    }
    #undef WF
}

extern "C" void kernel_launch(void* const* d_in, const int* in_sizes, int n_in,
                              void* d_out, int out_size, void* d_ws, size_t ws_size,
                              hipStream_t stream) {
    const float* points    = (const float*)d_in[0];
    const float* features  = (const float*)d_in[1];
    const float* w0        = (const float*)d_in[2];
    const float* w1        = (const float*)d_in[3];
    const float* w2        = (const float*)d_in[4];
    const float* gammas    = (const float*)d_in[5];
    const float* betas     = (const float*)d_in[6];
    const float* means     = (const float*)d_in[7];
    const float* variances = (const float*)d_in[8];
    const float* sc_w      = (const float*)d_in[9];
    const float* sc_gamma  = (const float*)d_in[10];
    const float* sc_beta   = (const float*)d_in[11];
    const float* sc_mean   = (const float*)d_in[12];
    const float* sc_var    = (const float*)d_in[13];
    float* out = (float*)d_out;

    int* knn_buf = (int*)d_ws;                                          // 2 MB
    unsigned short* fbf = (unsigned short*)((char*)d_ws + (1 << 21));   // 4 MB
    unsigned short* wsf = (unsigned short*)((char*)d_ws + (3 << 21));   // 40 KB
    float* bnp = (float*)((char*)d_ws + (3 << 21) + 40960);             // 2 KB

    setup_kernel<<<1361, 256, 0, stream>>>(points, features, w0, w1, w2, sc_w,
                                           gammas, betas, means, variances,
                                           sc_gamma, sc_beta, sc_mean, sc_var,
                                           fbf, wsf, bnp, knn_buf);
    edge_kernel<<<NBATCH * NP / 32, 256, 0, stream>>>(fbf, knn_buf, wsf, bnp, out);
}

// Round 14
// 46.642 us; speedup vs baseline: 1.6825x; 1.0075x over previous
//
#include <hip/hip_runtime.h>
#include <math.h>

#define NBATCH 128
#define NP 256
#define NC 64
#define KNN 16
#define EPSV 1e-3f

typedef __bf16 bf16_t;
typedef bf16_t bf16x8 __attribute__((ext_vector_type(8)));
typedef float f32x4 __attribute__((ext_vector_type(4)));
typedef unsigned short u16x4 __attribute__((ext_vector_type(4)));

static __device__ __forceinline__ f32x4 mfma16(bf16x8 a, bf16x8 b, f32x4 c) {
    return __builtin_amdgcn_mfma_f32_16x16x32_bf16(a, b, c, 0, 0, 0);
}
static __device__ __forceinline__ unsigned short f2bfu(float f) {
    union { bf16_t b; unsigned short u; } cv; cv.b = (bf16_t)f; return cv.u;
}
static __device__ __forceinline__ unsigned umin2(unsigned a, unsigned b) { return a < b ? a : b; }
static __device__ __forceinline__ unsigned umax2(unsigned a, unsigned b) { return a > b ? a : b; }
static __device__ __forceinline__ float bperm_f32(int idx, float v) {
    return __int_as_float(__builtin_amdgcn_ds_bpermute(idx, __float_as_int(v)));
}

// Compiler-only ordering fence (R11-validated): wave-private LDS + in-order
// per-wave DS pipe -> no HW drain needed. Zero instructions.
#define CFENCE() asm volatile("" ::: "memory")

// Sorted-ascending insert, med3 form (2 ops/level, levels independent).
#define INSERTK(k_)                                                   \
    do {                                                              \
        _Pragma("unroll")                                             \
        for (int ii = KNN - 1; ii >= 1; --ii)                         \
            bk[ii] = umin2(umax2((k_), bk[ii - 1]), bk[ii]);          \
        bk[0] = umin2((k_), bk[0]);                                   \
    } while (0)

// ---------------------------------------------------------------------------
// setup_kernel: fused fcvt + prep + knn (one dispatch).
//   blocks [0,1024)    : fcvt  — features f32 -> bf16
//   blocks [1024,1105) : prep  — weight B-frags (channel-permuted) + BN fold
//   blocks [1105,1361) : knn   — packed-key 2-way split kNN
// ---------------------------------------------------------------------------
__global__ __launch_bounds__(256) void setup_kernel(
    const float* __restrict__ points, const float* __restrict__ features,
    const float* __restrict__ w0, const float* __restrict__ w1,
    const float* __restrict__ w2, const float* __restrict__ sc_w,
    const float* __restrict__ gammas, const float* __restrict__ betas,
    const float* __restrict__ means, const float* __restrict__ variances,
    const float* __restrict__ sc_gamma, const float* __restrict__ sc_beta,
    const float* __restrict__ sc_mean, const float* __restrict__ sc_var,
    unsigned short* __restrict__ fbf, unsigned short* __restrict__ wsf,
    float* __restrict__ bnp, int* __restrict__ knn_out)
{
    const int bid = blockIdx.x;
    if (bid < 1024) {
        // ---- fcvt section ----
        const int tid = bid * 256 + threadIdx.x;
        const float4 a = ((const float4*)features)[tid * 2];
        const float4 b = ((const float4*)features)[tid * 2 + 1];
        union { unsigned short s[8]; uint4 v; } r;
        r.s[0] = f2bfu(a.x); r.s[1] = f2bfu(a.y); r.s[2] = f2bfu(a.z); r.s[3] = f2bfu(a.w);
        r.s[4] = f2bfu(b.x); r.s[5] = f2bfu(b.y); r.s[6] = f2bfu(b.z); r.s[7] = f2bfu(b.w);
        ((uint4*)fbf)[tid] = r.v;
    } else if (bid < 1105) {
        // ---- prep section: channel-permuted B-frags ----
        const int tid = (bid - 1024) * 256 + threadIdx.x;
        if (tid < 20480) {
            const int region = tid >> 12;          // 0:V 1:w0hi 2:w1 3:w2 4:ws
            const int e2 = tid & 4095;
            const int f = e2 >> 9;
            const int r = e2 & 511;
            const int lane = r >> 3, j = r & 7;
            const int ks = f >> 2, t = f & 3;
            const int row = ks * 32 + (lane >> 4) * 8 + j;
            const int col = 4 * (lane & 15) + t;   // PERMUTED output channel
            float v;
            if (region == 0)      v = w0[row * 64 + col] - w0[(64 + row) * 64 + col];
            else if (region == 1) v = w0[(64 + row) * 64 + col];
            else if (region == 2) v = w1[row * 64 + col];
            else if (region == 3) v = w2[row * 64 + col];
            else                  v = sc_w[row * 64 + col];
            wsf[tid] = f2bfu(v);
        } else {
            const int e = tid - 20480;
            if (e < 192) {
                float s = gammas[e] * rsqrtf(variances[e] + EPSV);
                bnp[e] = s;
                bnp[192 + e] = betas[e] - means[e] * s;
            } else if (e < 256) {
                const int d = e - 192;
                float s = sc_gamma[d] * rsqrtf(sc_var[d] + EPSV);
                bnp[384 + d] = s;
                bnp[448 + d] = sc_beta[d] - sc_mean[d] * s;
            }
        }
    } else {
        // ---- knn section ----
        __shared__ __align__(16) float4 sp[NP];
        __shared__ unsigned sk[128][17];
        const int kb = bid - 1105;
        const int bb = kb >> 1;
        const int qbase = (kb & 1) * 128;
        const int t = threadIdx.x;
        const int qt = t & 127;
        const int half = t >> 7;
        const int p = qbase + qt;

        const float* pb = points + (size_t)bb * NP * 3;
        sp[t] = make_float4(pb[t * 3 + 0], pb[t * 3 + 1], pb[t * 3 + 2], 0.f);
        __syncthreads();

        const float4 qp = sp[p];
        unsigned bk[KNN];
#pragma unroll
        for (int i = 0; i < KNN; ++i) bk[i] = 0xFFFFFFFFu;

        const int cbase = half * 128;
#pragma unroll 4
        for (int c = 0; c < 128; ++c) {
            const int cand = cbase + c;
            const float4 P = sp[cand];
            const float dx = qp.x - P.x, dy = qp.y - P.y, dz = qp.z - P.z;
            const float d = fmaf(dx, dx, fmaf(dy, dy, dz * dz));
            unsigned key = (__float_as_uint(d) & 0xFFFFFF00u) | (unsigned)cand;
            key = (cand == p) ? 0xFFFFFFFFu : key;
            INSERTK(key);
        }

        if (half == 1) {
#pragma unroll
            for (int i = 0; i < KNN; ++i) sk[qt][i] = bk[i];
        }
        __syncthreads();
        if (half == 0) {
            for (int j = 0; j < KNN; ++j) {
                const unsigned key = sk[qt][j];
                if (key >= bk[KNN - 1]) break;
                INSERTK(key);
            }
            int* op = knn_out + ((size_t)bb * NP + p) * KNN;
#pragma unroll
            for (int i = 0; i < KNN; ++i) op[i] = (int)(bk[i] & 0xFFu);
        }
    }
}

// ---------------------------------------------------------------------------
// Edge MLP v10: LDS-shared weights (R13) + point-PAIRING with weight-read
// sharing (each layer's 8 weight frags read once, used by both chains) +
// s0 via ds_bpermute from the prologue C-frag registers (s0buf eliminated).
// LDS = 24K weights + 18K slabs + 8K fts = 51.2 KB -> 3 WG/CU, 12 waves/CU,
// 2 independent chains/wave = 6 streams/SIMD. DS traffic/point ~40% lower
// than R13 (weight reads halved, s0 reads replaced by bpermute).
// ---------------------------------------------------------------------------
__global__ __launch_bounds__(256) void edge_kernel(
    const unsigned short* __restrict__ fbf, const int* __restrict__ knn_idx,
    const unsigned short* __restrict__ wsf, const float* __restrict__ bnp,
    float* __restrict__ out)
{
    __shared__ __align__(16) unsigned short wlds[24 * 512];    // 24 KB shared frags
    __shared__ __align__(16) unsigned short slab[4][2][16 * 72]; // 18 KB
    __shared__ __align__(16) float ftsbuf[4][8][64];           // 8 KB

    const int tid = threadIdx.x;
    const int wid = tid >> 6;
    const int l = tid & 63;
    const int i = l & 15;
    const int h = l >> 4;
    // bijective XCD swizzle: 1024 blocks = 8 XCDs x 128 contiguous work items
    const int wg = (blockIdx.x & 7) * 128 + (blockIdx.x >> 3);
    const int p0 = (wg * 4 + wid) * 8;
    const int b = p0 >> 8;

    unsigned short* sl0 = slab[wid][0];
    unsigned short* sl1 = slab[wid][1];

    // ---- cooperative load of main-loop weight frags (w0hi,w1,w2) -> LDS ----
    {
        const uint4* src = (const uint4*)(wsf + 4096);
        uint4* dst = (uint4*)wlds;
#pragma unroll
        for (int k = 0; k < 6; ++k) dst[tid + k * 256] = src[tid + k * 256];
    }
    #define WF(fi_) (*(const bf16x8*)&wlds[(fi_) * 512 + l * 8])

    // BN params: lane's channels are 4i..4i+3 -> float4 loads
    float4 scl[3], shf[3];
#pragma unroll
    for (int L = 0; L < 3; ++L) {
        scl[L] = *(const float4*)&bnp[L * 64 + 4 * i];
        shf[L] = *(const float4*)&bnp[192 + L * 64 + 4 * i];
    }

    // ---- prologue: s0 = ctr @ V, kept in REGISTERS (C-frag layout).
    // s0acc[t][r] = channel 4i+t of point (4h+r)&7; main loop fetches via
    // bpermute from lane (q>>2)*16+i.
    f32x4 s0acc[4];
    {
        const bf16x8* __restrict__ WV = (const bf16x8*)(wsf);
        const unsigned short* cp = fbf + (size_t)(p0 + (i & 7)) * NC;
        bf16x8 a0 = *(const bf16x8*)(cp + 8 * h);
        bf16x8 a1 = *(const bf16x8*)(cp + 32 + 8 * h);
#pragma unroll
        for (int t = 0; t < 4; ++t) {
            f32x4 z = {0.f, 0.f, 0.f, 0.f};
            z = mfma16(a0, WV[t * 64 + l], z);
            s0acc[t] = mfma16(a1, WV[(4 + t) * 64 + l], z);
        }
    }
    int nks[8];
#pragma unroll
    for (int q = 0; q < 8; ++q) nks[q] = knn_idx[(size_t)(p0 + q) * KNN + i];

    __syncthreads();   // weights visible to all 4 waves

    const int i4 = 4 * i;   // bpermute byte-index base

    // prime pair 0's neighbor A-fragments
    bf16x8 f00, f01, f10, f11;
    {
        const unsigned short* sp0 = fbf + (size_t)(b * NP + nks[0]) * NC;
        const unsigned short* sp1 = fbf + (size_t)(b * NP + nks[1]) * NC;
        f00 = *(const bf16x8*)(sp0 + 8 * h);
        f01 = *(const bf16x8*)(sp0 + 32 + 8 * h);
        f10 = *(const bf16x8*)(sp1 + 8 * h);
        f11 = *(const bf16x8*)(sp1 + 32 + 8 * h);
    }

#pragma unroll
    for (int qp = 0; qp < 4; ++qp) {
        const int q0 = 2 * qp, q1 = 2 * qp + 1;
        // ---- s0 for the pair via bpermute (issued early; hides under MFMA) ----
        const int idxp = (qp >> 1) * 64 + i4;   // src lane = (q>>2)*16 + i
        float s0a[4], s0b[4];
#pragma unroll
        for (int t = 0; t < 4; ++t) {
            s0a[t] = bperm_f32(idxp, s0acc[t][q0 & 3]);
            s0b[t] = bperm_f32(idxp, s0acc[t][q1 & 3]);
        }

        // ---- L1 phase: weight frags read once, both chains ----
        {
            f32x4 accA[4], accB[4];
#pragma unroll
            for (int t = 0; t < 4; ++t) {
                bf16x8 wt0 = WF(t);
                bf16x8 wt1 = WF(4 + t);
                f32x4 z = {0.f, 0.f, 0.f, 0.f};
                z = mfma16(f00, wt0, z);
                accA[t] = mfma16(f01, wt1, z);
                z = (f32x4){0.f, 0.f, 0.f, 0.f};
                z = mfma16(f10, wt0, z);
                accB[t] = mfma16(f11, wt1, z);
            }
            const float* sc_ = (const float*)&scl[0];
            const float* sh_ = (const float*)&shf[0];
#pragma unroll
            for (int r = 0; r < 4; ++r) {
                u16x4 pkA, pkB;
#pragma unroll
                for (int t = 0; t < 4; ++t) {
                    pkA[t] = f2bfu(fmaxf(fmaf(accA[t][r] + s0a[t], sc_[t], sh_[t]), 0.f));
                    pkB[t] = f2bfu(fmaxf(fmaf(accB[t][r] + s0b[t], sc_[t], sh_[t]), 0.f));
                }
                *(u16x4*)&sl0[(h * 4 + r) * 72 + i4] = pkA;
                *(u16x4*)&sl1[(h * 4 + r) * 72 + i4] = pkB;
            }
        }
        // prefetch next pair's fragments (global loads ahead of LDS phases)
        bf16x8 g00, g01, g10, g11;
        if (qp < 3) {
            const unsigned short* sp0 = fbf + (size_t)(b * NP + nks[(q0 + 2) & 7]) * NC;
            const unsigned short* sp1 = fbf + (size_t)(b * NP + nks[(q1 + 2) & 7]) * NC;
            g00 = *(const bf16x8*)(sp0 + 8 * h);
            g01 = *(const bf16x8*)(sp0 + 32 + 8 * h);
            g10 = *(const bf16x8*)(sp1 + 8 * h);
            g11 = *(const bf16x8*)(sp1 + 32 + 8 * h);
        }
        CFENCE();  // L1 writes ordered before L2 reads

        // ---- L2 phase (in-place, both chains, shared weight reads) ----
        {
            bf16x8 xa0 = *(const bf16x8*)(sl0 + i * 72 + h * 8);
            bf16x8 xa1 = *(const bf16x8*)(sl0 + i * 72 + h * 8 + 32);
            bf16x8 xb0 = *(const bf16x8*)(sl1 + i * 72 + h * 8);
            bf16x8 xb1 = *(const bf16x8*)(sl1 + i * 72 + h * 8 + 32);
            f32x4 accA[4], accB[4];
#pragma unroll
            for (int t = 0; t < 4; ++t) {
                bf16x8 wt0 = WF(8 + t);
                bf16x8 wt1 = WF(12 + t);
                f32x4 z = {0.f, 0.f, 0.f, 0.f};
                z = mfma16(xa0, wt0, z);
                accA[t] = mfma16(xa1, wt1, z);
                z = (f32x4){0.f, 0.f, 0.f, 0.f};
                z = mfma16(xb0, wt0, z);
                accB[t] = mfma16(xb1, wt1, z);
            }
            const float* sc_ = (const float*)&scl[1];
            const float* sh_ = (const float*)&shf[1];
#pragma unroll
            for (int r = 0; r < 4; ++r) {
                u16x4 pkA, pkB;
#pragma unroll
                for (int t = 0; t < 4; ++t) {
                    pkA[t] = f2bfu(fmaxf(fmaf(accA[t][r], sc_[t], sh_[t]), 0.f));
                    pkB[t] = f2bfu(fmaxf(fmaf(accB[t][r], sc_[t], sh_[t]), 0.f));
                }
                *(u16x4*)&sl0[(h * 4 + r) * 72 + i4] = pkA;
                *(u16x4*)&sl1[(h * 4 + r) * 72 + i4] = pkB;
            }
        }
        CFENCE();  // L2 writes ordered before L3 reads

        // ---- L3 phase + mean over k (both chains, shared weight reads) ----
        {
            bf16x8 xa0 = *(const bf16x8*)(sl0 + i * 72 + h * 8);
            bf16x8 xa1 = *(const bf16x8*)(sl0 + i * 72 + h * 8 + 32);
            bf16x8 xb0 = *(const bf16x8*)(sl1 + i * 72 + h * 8);
            bf16x8 xb1 = *(const bf16x8*)(sl1 + i * 72 + h * 8 + 32);
            const float* sc_ = (const float*)&scl[2];
            const float* sh_ = (const float*)&shf[2];
            float sa[4], sb[4];
#pragma unroll
            for (int t = 0; t < 4; ++t) {
                bf16x8 wt0 = WF(16 + t);
                bf16x8 wt1 = WF(20 + t);
                f32x4 z = {0.f, 0.f, 0.f, 0.f};
                z = mfma16(xa0, wt0, z);
                f32x4 accA = mfma16(xa1, wt1, z);
                z = (f32x4){0.f, 0.f, 0.f, 0.f};
                z = mfma16(xb0, wt0, z);
                f32x4 accB = mfma16(xb1, wt1, z);
                float s = 0.f, sB = 0.f;
#pragma unroll
                for (int r = 0; r < 4; ++r) {
                    s += fmaxf(fmaf(accA[r], sc_[t], sh_[t]), 0.f);
                    sB += fmaxf(fmaf(accB[r], sc_[t], sh_[t]), 0.f);
                }
                s += __shfl_xor(s, 16, 64);
                s += __shfl_xor(s, 32, 64);
                sB += __shfl_xor(sB, 16, 64);
                sB += __shfl_xor(sB, 32, 64);
                sa[t] = s * (1.f / 16.f);
                sb[t] = sB * (1.f / 16.f);
            }
            if (h == 0) {
                *(float4*)&ftsbuf[wid][q0][i4] = make_float4(sa[0], sa[1], sa[2], sa[3]);
                *(float4*)&ftsbuf[wid][q1][i4] = make_float4(sb[0], sb[1], sb[2], sb[3]);
            }
        }
        CFENCE();  // WAR before next pair's L1 writes
        f00 = g00; f01 = g01; f10 = g10; f11 = g11;
    }

    // ---- shortcut GEMM + epilogue (WS frags from GLOBAL, one-shot) ----
    {
        const bf16x8* __restrict__ WS = (const bf16x8*)(wsf + 16384);
        float4 sscl = *(const float4*)&bnp[384 + i4];
        float4 sshf = *(const float4*)&bnp[448 + i4];
        const unsigned short* fp = fbf + (size_t)(p0 + (i & 7)) * NC;
        bf16x8 a0 = *(const bf16x8*)(fp + 8 * h);
        bf16x8 a1 = *(const bf16x8*)(fp + 32 + 8 * h);
        f32x4 acc[4];
#pragma unroll
        for (int t = 0; t < 4; ++t) {
            f32x4 z = {0.f, 0.f, 0.f, 0.f};
            z = mfma16(a0, WS[t * 64 + l], z);
            acc[t] = mfma16(a1, WS[(4 + t) * 64 + l], z);
        }
        if (h < 2) {
            const float* ss_ = (const float*)&sscl;
            const float* sf_ = (const float*)&sshf;
#pragma unroll
            for (int r = 0; r < 4; ++r) {
                const int q = h * 4 + r;
                float4 fts = *(const float4*)&ftsbuf[wid][q][i4];
                const float* ft_ = (const float*)&fts;
                float4 o;
                float* o_ = (float*)&o;
#pragma unroll
                for (int t = 0; t < 4; ++t)
                    o_[t] = fmaxf(fmaf(acc[t][r], ss_[t], sf_[t]) + ft_[t], 0.f);
                *(float4*)&out[(size_t)(p0 + q) * NC + i4] = o;
            }
        }
    }
    #undef WF
}

extern "C" void kernel_launch(void* const* d_in, const int* in_sizes, int n_in,
                              void* d_out, int out_size, void* d_ws, size_t ws_size,
                              hipStream_t stream) {
    const float* points    = (const float*)d_in[0];
    const float* features  = (const float*)d_in[1];
    const float* w0        = (const float*)d_in[2];
    const float* w1        = (const float*)d_in[3];
    const float* w2        = (const float*)d_in[4];
    const float* gammas    = (const float*)d_in[5];
    const float* betas     = (const float*)d_in[6];
    const float* means     = (const float*)d_in[7];
    const float* variances = (const float*)d_in[8];
    const float* sc_w      = (const float*)d_in[9];
    const float* sc_gamma  = (const float*)d_in[10];
    const float* sc_beta   = (const float*)d_in[11];
    const float* sc_mean   = (const float*)d_in[12];
    const float* sc_var    = (const float*)d_in[13];
    float* out = (float*)d_out;

    int* knn_buf = (int*)d_ws;                                          // 2 MB
    unsigned short* fbf = (unsigned short*)((char*)d_ws + (1 << 21));   // 4 MB
    unsigned short* wsf = (unsigned short*)((char*)d_ws + (3 << 21));   // 40 KB
    float* bnp = (float*)((char*)d_ws + (3 << 21) + 40960);             // 2 KB

    setup_kernel<<<1361, 256, 0, stream>>>(points, features, w0, w1, w2, sc_w,
                                           gammas, betas, means, variances,
                                           sc_gamma, sc_beta, sc_mean, sc_var,
                                           fbf, wsf, bnp, knn_buf);
    edge_kernel<<<NBATCH * NP / 32, 256, 0, stream>>>(fbf, knn_buf, wsf, bnp, out);
}